// Round 8
// baseline (307.999 us; speedup 1.0000x reference)
//
#include <hip/hip_runtime.h>
#include <math.h>

#define N_NODES 50000
#define N_EDGES 400000
#define R_REL   35
#define B_BASES 12
#define C_DIM   128
#define HL_DIM  38
#define RI2     70
#define NBUCK2  782           // ceil(50000/64) — bucket = dst>>6 (NO permutation)
#define EPB     1024          // edges per scatter block
#define NEB     391           // edge blocks (512 threads): 391*1024 >= 400000
#define NWTB    18            // wT role blocks (512 t): 18*512 >= 8960
#define NPADB   8             // W-pad role blocks (512 t)
#define CAP     704           // bucket capacity (mean 512, 8.5 sigma)

// ---- ws float offsets ----
#define OFF_WT     0          // w[ri][c] = [70][128] = 8960
#define OFF_ECUR   110992     // int[782] bucket cursors (zeroed by memset)
#define OFF_EREC   111780     // float4[782*704] (16B aligned)
// padded per-type weight copies (rows stride 40 -> 16B-aligned float4 reads)
#define OFF_W0P    2325156    // [4][128][40] = 20480 floats
#define OFF_W1P    2345636    // [4][38][40]  = 6080 floats
#define OFF_W2P    2351716    // [4][38][40]  = 6080 floats

// ---- k_node LDS float offsets (33.3 KB) ----
#define ST    0
#define HH    0
#define Y0T   0
#define Y1T   3264
#define Y2T   0
#define SM_DINV 8192  // [64] f32
#define SM_TY   8256  // [64] int (node types)
#define LDS_FLOATS 8334

// D2 (k_escatter): blocks 0..390 edge scatter (projections computed inline per block);
// blocks 391..408 wT compute; blocks 409..416 padded W0/W1/W2 copies.
__global__ __launch_bounds__(512) void k_escatter(const float* __restrict__ x,
                                                  const int* __restrict__ edge_index,
                                                  const int* __restrict__ edge_type,
                                                  const float* __restrict__ edge_attr,
                                                  const float* __restrict__ basis,
                                                  const float* __restrict__ att_rel,
                                                  const float* __restrict__ q_att,
                                                  const float* __restrict__ k_att,
                                                  const float* __restrict__ e_att,
                                                  const float* __restrict__ lin_edge_W,
                                                  const float* __restrict__ lin0_W,
                                                  const float* __restrict__ lin1_W,
                                                  const float* __restrict__ lin2_W,
                                                  float* __restrict__ ws) {
    int b = blockIdx.x, tid = threadIdx.x;
    int lane = tid & 63, wv = tid >> 6;      // 8 waves

    if (b >= NEB) {
        if (b < NEB + NWTB) {
            int idx = (b - NEB) * 512 + tid;
            if (idx < RI2 * C_DIM) {
                int c  = idx & (C_DIM - 1);
                int ri = idx >> 7;
                int r = ri >> 1, ii = ri & 1;
                float acc = 0.f;
                #pragma unroll
                for (int bb = 0; bb < B_BASES; ++bb)
                    acc += att_rel[r * B_BASES + bb] * basis[(bb * 2 + ii) * C_DIM + c];
                ws[OFF_WT + idx] = acc;
            }
        } else {
            int g = (b - (NEB + NWTB)) * 512 + tid;   // 0..4095
            for (int idx = g; idx < 4 * C_DIM * HL_DIM; idx += NPADB * 512) {
                int tt = idx / (C_DIM * HL_DIM);
                int rem = idx - tt * (C_DIM * HL_DIM);
                int cc = rem / HL_DIM, j = rem - cc * HL_DIM;
                ws[OFF_W0P + tt * (C_DIM * 40) + cc * 40 + j] = lin0_W[idx];
            }
            for (int idx = g; idx < 4 * HL_DIM * HL_DIM; idx += NPADB * 512) {
                int tt = idx / (HL_DIM * HL_DIM);
                int rem = idx - tt * (HL_DIM * HL_DIM);
                int cc = rem / HL_DIM, j = rem - cc * HL_DIM;
                ws[OFF_W1P + tt * (HL_DIM * 40) + cc * 40 + j] = lin1_W[idx];
                ws[OFF_W2P + tt * (HL_DIM * 40) + cc * 40 + j] = lin2_W[idx];
            }
        }
        return;
    }

    __shared__ int hist[NBUCK2];
    __shared__ int sbase[NBUCK2];
    __shared__ float swq[RI2], swk[RI2], sle[2];
    __shared__ float s_dot[64];

    for (int i = tid; i < NBUCK2; i += 512) hist[i] = 0;

    // inline projections: 50 length-128 dots over 8 waves
    // tasks 0..23: basis row . q_att ; 24..47: basis row . k_att ; 48..49: lin_edge . e_att
    for (int task = wv; task < 50; task += 8) {
        const float* v;
        const float* o;
        if (task < 24)      { v = basis + task * C_DIM;             o = q_att; }
        else if (task < 48) { v = basis + (task - 24) * C_DIM;      o = k_att; }
        else                { v = lin_edge_W + (task - 48) * C_DIM; o = e_att; }
        float s = v[lane] * o[lane] + v[64 + lane] * o[64 + lane];
        #pragma unroll
        for (int off = 32; off; off >>= 1) s += __shfl_xor(s, off, 64);
        if (lane == 0) s_dot[task] = s;
    }
    __syncthreads();
    if (tid < RI2) {
        int r = tid >> 1, ii = tid & 1;
        float a1 = 0.f, a2 = 0.f;
        #pragma unroll
        for (int bb = 0; bb < B_BASES; ++bb) {
            float a = att_rel[r * B_BASES + bb];
            a1 += a * s_dot[2 * bb + ii];
            a2 += a * s_dot[24 + 2 * bb + ii];
        }
        swq[tid] = a1;
        swk[tid] = a2;
    } else if (tid < RI2 + 2) {
        sle[tid - RI2] = s_dot[48 + tid - RI2];
    }
    __syncthreads();

    int base = b * EPB;
    int   rb[2], rm[2];
    float rex[2], rsx[2], rsy[2];
    #pragma unroll
    for (int k = 0; k < 2; ++k) {
        int e = base + k * 512 + tid;
        rb[k] = -1;
        if (e < N_EDGES) {
            int src = edge_index[e];
            int dst = edge_index[N_EDGES + e];
            int r   = edge_type[e];
            float2 ea = *(const float2*)(edge_attr + 2 * e);
            float2 xs = *(const float2*)(x + 2 * src);
            float2 xd = *(const float2*)(x + 2 * dst);
            float alpha = xd.x * swq[2 * r] + xd.y * swq[2 * r + 1]
                        + xs.x * swk[2 * r] + xs.y * swk[2 * r + 1]
                        + ea.x * sle[0]     + ea.y * sle[1];
            alpha = alpha > 0.f ? alpha : 0.2f * alpha;
            float ex = __expf(alpha);
            rb[k]  = dst >> 6;                       // natural-order bucket
            rm[k]  = (r << 6) | (dst & 63);
            rex[k] = ex;
            rsx[k] = ex * xs.x;
            rsy[k] = ex * xs.y;
            atomicAdd(&hist[rb[k]], 1);
        }
    }
    __syncthreads();
    int* gcur = (int*)(ws + OFF_ECUR);
    for (int i = tid; i < NBUCK2; i += 512) {
        int c = hist[i];
        sbase[i] = (c > 0) ? atomicAdd(&gcur[i], c) : 0;
    }
    __syncthreads();
    float4* rec = (float4*)(ws + OFF_EREC);
    #pragma unroll
    for (int k = 0; k < 2; ++k) {
        if (rb[k] >= 0) {
            int slot = atomicAdd(&sbase[rb[k]], 1);
            rec[(size_t)rb[k] * CAP + slot] =
                make_float4(__int_as_float(rm[k]), rex[k], rsx[k], rsy[k]);
        }
    }
}

// D3 (k_node): mixed-type 64-node tiles — per-node type-indexed weight pointers.
// GEMM1/epilogue1 type-independent (unchanged); GEMM2-4 load 4 w-rows per k-iter
// (L2 broadcast hits); final reads fin_W/fin_b per node type; direct out[p] write.
__global__ __launch_bounds__(256, 4) void k_node(
        const float* __restrict__ ws, const int* __restrict__ node_type,
        const float* __restrict__ conv_bias,
        const float* __restrict__ lin0_b, const float* __restrict__ lin1_b,
        const float* __restrict__ lin2_b, const float* __restrict__ fin_W,
        const float* __restrict__ fin_b, float* __restrict__ out) {
    __shared__ float L[LDS_FLOATS];
    int tid  = threadIdx.x;
    int lane = tid & 63;
    int wv   = tid >> 6;
    int p0   = blockIdx.x * 64;

    // ---------- phase 0: zero sT + den; stage node types
    for (int i4 = tid; i4 < (RI2 * 68) / 4; i4 += 256)
        *(float4*)&L[ST + i4 * 4] = make_float4(0.f, 0.f, 0.f, 0.f);
    if (tid < 64) {
        L[SM_DINV + tid] = 0.f;
        ((int*)&L[SM_TY])[tid] = (p0 + tid < N_NODES) ? node_type[p0 + tid] : 0;
    }
    __syncthreads();   // B1

    // ---------- phase 1: accumulate this bucket's edge records (LDS atomics)
    {
        int ecnt = ((const int*)(ws + OFF_ECUR))[blockIdx.x];
        const float4* rec = (const float4*)(ws + OFF_EREC) + (size_t)blockIdx.x * CAP;
        for (int i = tid; i < ecnt; i += 256) {
            float4 v = rec[i];
            int m = __float_as_int(v.x);
            int n = m & 63, r = m >> 6;
            atomicAdd(&L[ST + (2 * r) * 68 + n],     v.z);
            atomicAdd(&L[ST + (2 * r + 1) * 68 + n], v.w);
            atomicAdd(&L[SM_DINV + n],               v.y);
        }
    }
    __syncthreads();   // B2
    if (tid < 64) L[SM_DINV + tid] = 1.0f / (L[SM_DINV + tid] + 1e-16f);

    // ---------- GEMM1: H[64n x 128c] = sT x wT (type-independent)
    int ng = lane & 15, cg_ = lane >> 4;
    int c0 = wv * 32 + cg_ * 8;
    const float* wTg = ws + OFF_WT;
    float acc[32];
    #pragma unroll
    for (int i = 0; i < 32; ++i) acc[i] = 0.f;
    #pragma unroll 5
    for (int kk = 0; kk < RI2; ++kk) {
        float4 a4 = *(const float4*)&L[ST + kk * 68 + ng * 4];
        float4 wa = *(const float4*)&wTg[kk * 128 + c0];
        float4 wc = *(const float4*)&wTg[kk * 128 + c0 + 4];
        float a_[4] = {a4.x, a4.y, a4.z, a4.w};
        float w_[8] = {wa.x, wa.y, wa.z, wa.w, wc.x, wc.y, wc.z, wc.w};
        #pragma unroll
        for (int ni = 0; ni < 4; ++ni)
            #pragma unroll
            for (int ci = 0; ci < 8; ++ci)
                acc[ni * 8 + ci] += a_[ni] * w_[ci];
    }
    __syncthreads();   // B3

    // epilogue 1: h = relu(acc*dinv + cb) -> H[c][n]
    {
        float4 dv = *(const float4*)&L[SM_DINV + ng * 4];
        float d_[4] = {dv.x, dv.y, dv.z, dv.w};
        #pragma unroll
        for (int ci = 0; ci < 8; ++ci) {
            float cb = conv_bias[c0 + ci];
            float4 hv;
            float h0 = acc[0 * 8 + ci] * d_[0] + cb;
            float h1 = acc[1 * 8 + ci] * d_[1] + cb;
            float h2 = acc[2 * 8 + ci] * d_[2] + cb;
            float h3 = acc[3 * 8 + ci] * d_[3] + cb;
            hv.x = h0 > 0.f ? h0 : 0.f;
            hv.y = h1 > 0.f ? h1 : 0.f;
            hv.z = h2 > 0.f ? h2 : 0.f;
            hv.w = h3 > 0.f ? h3 : 0.f;
            *(float4*)&L[HH + (c0 + ci) * 64 + ng * 4] = hv;
        }
    }
    __syncthreads();   // B4: H ready; SM_TY stable (never overwritten)

    // per-thread node types for GEMM2-4 (nodes ng*4 .. ng*4+3)
    const int* sty = (const int*)&L[SM_TY];
    int t0_ = sty[ng * 4 + 0], t1_ = sty[ng * 4 + 1];
    int t2_ = sty[ng * 4 + 2], t3_ = sty[ng * 4 + 3];

    // ---------- GEMM2: y0 = H x W0[type(node)] — waves 0..2
    int jg = lane >> 4;
    int j0 = wv * 16 + jg * 4;
    float acc2[16];
    #pragma unroll
    for (int i = 0; i < 16; ++i) acc2[i] = 0.f;
    if (wv < 3) {
        const float* W0n0 = ws + OFF_W0P + t0_ * (C_DIM * 40) + j0;
        const float* W0n1 = ws + OFF_W0P + t1_ * (C_DIM * 40) + j0;
        const float* W0n2 = ws + OFF_W0P + t2_ * (C_DIM * 40) + j0;
        const float* W0n3 = ws + OFF_W0P + t3_ * (C_DIM * 40) + j0;
        #pragma unroll 4
        for (int kk = 0; kk < C_DIM; ++kk) {
            float4 a4 = *(const float4*)&L[HH + kk * 64 + ng * 4];
            float4 w0 = *(const float4*)&W0n0[kk * 40];
            float4 w1 = *(const float4*)&W0n1[kk * 40];
            float4 w2 = *(const float4*)&W0n2[kk * 40];
            float4 w3 = *(const float4*)&W0n3[kk * 40];
            acc2[0]  += a4.x * w0.x; acc2[1]  += a4.x * w0.y;
            acc2[2]  += a4.x * w0.z; acc2[3]  += a4.x * w0.w;
            acc2[4]  += a4.y * w1.x; acc2[5]  += a4.y * w1.y;
            acc2[6]  += a4.y * w1.z; acc2[7]  += a4.y * w1.w;
            acc2[8]  += a4.z * w2.x; acc2[9]  += a4.z * w2.y;
            acc2[10] += a4.z * w2.z; acc2[11] += a4.z * w2.w;
            acc2[12] += a4.w * w3.x; acc2[13] += a4.w * w3.y;
            acc2[14] += a4.w * w3.z; acc2[15] += a4.w * w3.w;
        }
    }
    __syncthreads();   // B5: all H reads done

    // epilogue 2 (waves 0..2): relu(y0 + b0[type(node)]) -> Y0T
    if (wv < 3) {
        int t4_[4] = {t0_, t1_, t2_, t3_};
        #pragma unroll
        for (int ji = 0; ji < 4; ++ji) {
            int j = j0 + ji;
            float4 yv;
            float y_[4];
            #pragma unroll
            for (int ni = 0; ni < 4; ++ni) {
                float bb = (j < HL_DIM) ? lin0_b[t4_[ni] * HL_DIM + j] : 0.f;
                float y = acc2[ni * 4 + ji] + bb;
                y_[ni] = y > 0.f ? y : 0.f;
            }
            yv.x = y_[0]; yv.y = y_[1]; yv.z = y_[2]; yv.w = y_[3];
            *(float4*)&L[Y0T + j * 68 + ng * 4] = yv;
        }
    }
    __syncthreads();   // B6: Y0T complete

    // ---------- GEMM3: y1 = y0 x W1[type(node)] (k=38); waves 0..2 -> Y1T
    if (wv < 3) {
        const float* W1n0 = ws + OFF_W1P + t0_ * (HL_DIM * 40) + j0;
        const float* W1n1 = ws + OFF_W1P + t1_ * (HL_DIM * 40) + j0;
        const float* W1n2 = ws + OFF_W1P + t2_ * (HL_DIM * 40) + j0;
        const float* W1n3 = ws + OFF_W1P + t3_ * (HL_DIM * 40) + j0;
        float acc3[16];
        #pragma unroll
        for (int i = 0; i < 16; ++i) acc3[i] = 0.f;
        #pragma unroll 2
        for (int kk = 0; kk < HL_DIM; ++kk) {
            float4 a4 = *(const float4*)&L[Y0T + kk * 68 + ng * 4];
            float4 w0 = *(const float4*)&W1n0[kk * 40];
            float4 w1 = *(const float4*)&W1n1[kk * 40];
            float4 w2 = *(const float4*)&W1n2[kk * 40];
            float4 w3 = *(const float4*)&W1n3[kk * 40];
            acc3[0]  += a4.x * w0.x; acc3[1]  += a4.x * w0.y;
            acc3[2]  += a4.x * w0.z; acc3[3]  += a4.x * w0.w;
            acc3[4]  += a4.y * w1.x; acc3[5]  += a4.y * w1.y;
            acc3[6]  += a4.y * w1.z; acc3[7]  += a4.y * w1.w;
            acc3[8]  += a4.z * w2.x; acc3[9]  += a4.z * w2.y;
            acc3[10] += a4.z * w2.z; acc3[11] += a4.z * w2.w;
            acc3[12] += a4.w * w3.x; acc3[13] += a4.w * w3.y;
            acc3[14] += a4.w * w3.z; acc3[15] += a4.w * w3.w;
        }
        int t4_[4] = {t0_, t1_, t2_, t3_};
        #pragma unroll
        for (int ji = 0; ji < 4; ++ji) {
            int j = j0 + ji;
            float4 yv;
            float y_[4];
            #pragma unroll
            for (int ni = 0; ni < 4; ++ni) {
                float bb = (j < HL_DIM) ? lin1_b[t4_[ni] * HL_DIM + j] : 0.f;
                float y = acc3[ni * 4 + ji] + bb;
                y_[ni] = y > 0.f ? y : 0.f;
            }
            yv.x = y_[0]; yv.y = y_[1]; yv.z = y_[2]; yv.w = y_[3];
            *(float4*)&L[Y1T + j * 68 + ng * 4] = yv;
        }
    }
    __syncthreads();   // B7: Y1T complete; Y0T reads done

    // ---------- GEMM4: y2 = y1 x W2[type(node)] (no relu); waves 0..2 -> Y2T
    if (wv < 3) {
        const float* W2n0 = ws + OFF_W2P + t0_ * (HL_DIM * 40) + j0;
        const float* W2n1 = ws + OFF_W2P + t1_ * (HL_DIM * 40) + j0;
        const float* W2n2 = ws + OFF_W2P + t2_ * (HL_DIM * 40) + j0;
        const float* W2n3 = ws + OFF_W2P + t3_ * (HL_DIM * 40) + j0;
        float acc4[16];
        #pragma unroll
        for (int i = 0; i < 16; ++i) acc4[i] = 0.f;
        #pragma unroll 2
        for (int kk = 0; kk < HL_DIM; ++kk) {
            float4 a4 = *(const float4*)&L[Y1T + kk * 68 + ng * 4];
            float4 w0 = *(const float4*)&W2n0[kk * 40];
            float4 w1 = *(const float4*)&W2n1[kk * 40];
            float4 w2 = *(const float4*)&W2n2[kk * 40];
            float4 w3 = *(const float4*)&W2n3[kk * 40];
            acc4[0]  += a4.x * w0.x; acc4[1]  += a4.x * w0.y;
            acc4[2]  += a4.x * w0.z; acc4[3]  += a4.x * w0.w;
            acc4[4]  += a4.y * w1.x; acc4[5]  += a4.y * w1.y;
            acc4[6]  += a4.y * w1.z; acc4[7]  += a4.y * w1.w;
            acc4[8]  += a4.z * w2.x; acc4[9]  += a4.z * w2.y;
            acc4[10] += a4.z * w2.z; acc4[11] += a4.z * w2.w;
            acc4[12] += a4.w * w3.x; acc4[13] += a4.w * w3.y;
            acc4[14] += a4.w * w3.z; acc4[15] += a4.w * w3.w;
        }
        int t4_[4] = {t0_, t1_, t2_, t3_};
        #pragma unroll
        for (int ji = 0; ji < 4; ++ji) {
            int j = j0 + ji;
            float4 yv;
            float y_[4];
            #pragma unroll
            for (int ni = 0; ni < 4; ++ni) {
                float bb = (j < HL_DIM) ? lin2_b[t4_[ni] * HL_DIM + j] : 0.f;
                y_[ni] = acc4[ni * 4 + ji] + bb;
            }
            yv.x = y_[0]; yv.y = y_[1]; yv.z = y_[2]; yv.w = y_[3];
            *(float4*)&L[Y2T + j * 68 + ng * 4] = yv;
        }
    }
    __syncthreads();   // B8: Y2T complete

    // ---------- final: fin [38]->[2] per node type, thread-per-node (wave 0)
    if (tid < 64) {
        int p = p0 + tid;
        bool valid = p < N_NODES;
        int t = sty[tid];
        const float2* fwp = (const float2*)(fin_W + t * 76);
        float o0 = fin_b[t * 2], o1 = fin_b[t * 2 + 1];
        for (int jj = 0; jj < HL_DIM; ++jj) {
            float v = L[Y2T + jj * 68 + tid];
            float2 f = fwp[jj];
            o0 += v * f.x;
            o1 += v * f.y;
        }
        if (t == 0) o1 = fabsf(o1);
        if (valid) ((float2*)out)[p] = make_float2(o0, o1);
    }
}

extern "C" void kernel_launch(void* const* d_in, const int* in_sizes, int n_in,
                              void* d_out, int out_size, void* d_ws, size_t ws_size,
                              hipStream_t stream) {
    const float* x          = (const float*)d_in[0];
    const int*   edge_index = (const int*)  d_in[1];
    const int*   edge_type  = (const int*)  d_in[2];
    const float* edge_attr  = (const float*)d_in[3];
    const int*   node_type  = (const int*)  d_in[4];
    const float* basis      = (const float*)d_in[5];
    const float* att_rel    = (const float*)d_in[6];
    const float* q_att      = (const float*)d_in[7];
    const float* k_att      = (const float*)d_in[8];
    const float* e_att      = (const float*)d_in[9];
    const float* lin_edge_W = (const float*)d_in[10];
    const float* conv_bias  = (const float*)d_in[11];
    const float* lin0_W     = (const float*)d_in[12];
    const float* lin0_b     = (const float*)d_in[13];
    const float* lin1_W     = (const float*)d_in[14];
    const float* lin1_b     = (const float*)d_in[15];
    const float* lin2_W     = (const float*)d_in[16];
    const float* lin2_b     = (const float*)d_in[17];
    const float* fin_W      = (const float*)d_in[18];
    const float* fin_b      = (const float*)d_in[19];

    float* ws  = (float*)d_ws;
    float* out = (float*)d_out;

    hipMemsetAsync((char*)d_ws + (size_t)OFF_ECUR * 4, 0, NBUCK2 * 4, stream);
    k_escatter<<<NEB + NWTB + NPADB, 512, 0, stream>>>(x, edge_index, edge_type, edge_attr,
                                                       basis, att_rel, q_att, k_att, e_att,
                                                       lin_edge_W, lin0_W, lin1_W, lin2_W, ws);
    k_node    <<<NBUCK2, 256, 0, stream>>>(ws, node_type, conv_bias,
                                           lin0_b, lin1_b, lin2_b, fin_W, fin_b, out);
}

// Round 9
// 161.091 us; speedup vs baseline: 1.9120x; 1.9120x over previous
//
#include <hip/hip_runtime.h>
#include <math.h>

#define N_NODES 50000
#define N_EDGES 400000
#define R_REL   35
#define B_BASES 12
#define C_DIM   128
#define HL_DIM  38
#define RI2     70
#define BI2     24            // 2*B_BASES — projected K for GEMM1'
#define NP      50304         // padded permuted node space (mult of 64)
#define NB_HIST 196           // ceil(50000/256)
#define NBUCK   786           // NP/64 — one bucket per k_node tile
#define EPB     1024          // edges per scatter block (391*1024 >= 400000)
#define NEB     391           // escatter blocks (512 threads each)
#define CAP     704           // fixed bucket segment capacity (mean 512, 8.5 sigma)

// ---- ws float offsets ----
#define OFF_WQ     8960       // [70]
#define OFF_WK     9030       // [70]
#define OFF_LE     9100       // [2]
#define OFF_META   9104       // 16 ints: counts[4]@0, basel[4]@4
#define OFF_HBLK   9120       // int[196][4]
#define OFF_PERM   10688      // int[50000]
#define OFF_INV    60688      // int[NP]
#define OFF_ECUR   110992     // int[786] global bucket cursors
#define OFF_EREC   111780     // float4[786*704]  (16B aligned)
// padded per-type weight copies (rows stride 40 -> 16B-aligned float4 reads)
#define OFF_W0P    2325156    // [4][128][40] = 20480 floats
#define OFF_W1P    2345636    // [4][38][40]  = 6080 floats
#define OFF_W2P    2351716    // [4][38][40]  = 6080 floats

// ---- k_node LDS float offsets (33.3 KB) ----
#define ST    0               // sT[70][68]   [0,4760)
#define SB    4760            // sB[24][68]   [4760,6392) — basis-projected sT
#define HH    0               // H[128][64]   [0,8192)  (after GEMM1' reads done)
#define Y0T   0
#define Y1T   3264
#define Y2T   0
#define SM_DINV 8192  // [64]
#define SM_FW   8256  // [76]
#define SM_FB   8332  // [2]
#define LDS_FLOATS 8334

// D1 (k_hist): per-256-node-chunk type histogram (196 blocks) + cursor zero (block 196)
__global__ __launch_bounds__(256) void k_hist(const int* __restrict__ node_type,
                                              float* __restrict__ ws) {
    int b = blockIdx.x, tid = threadIdx.x;
    if (b >= NB_HIST) {
        for (int i = tid; i < NBUCK; i += 256) ((int*)(ws + OFF_ECUR))[i] = 0;
        return;
    }
    __shared__ int lh[4];
    if (tid < 4) lh[tid] = 0;
    __syncthreads();
    int i = b * 256 + tid;
    if (i < N_NODES) atomicAdd(&lh[node_type[i]], 1);
    __syncthreads();
    if (tid < 4) ((int*)(ws + OFF_HBLK))[b * 4 + tid] = lh[tid];
}

// D2 (k_perm2): blocks 0..195 permutation; roles appended:
// 196..231 attention projections (swq/swk/sle), 232..247 padded W0/W1/W2 copies.
// (wT precompute role DELETED — GEMM1' consumes basis directly.)
__global__ __launch_bounds__(256) void k_perm2(const int* __restrict__ node_type,
                                               const float* __restrict__ basis,
                                               const float* __restrict__ att_rel,
                                               const float* __restrict__ q_att,
                                               const float* __restrict__ k_att,
                                               const float* __restrict__ e_att,
                                               const float* __restrict__ lin_edge_W,
                                               const float* __restrict__ lin0_W,
                                               const float* __restrict__ lin1_W,
                                               const float* __restrict__ lin2_W,
                                               float* __restrict__ ws) {
    int b = blockIdx.x, tid = threadIdx.x;
    int lane = tid & 63, wv = tid >> 6;
    if (b >= NB_HIST) {
        if (b < NB_HIST + 36) {
            int u = (b - NB_HIST) * 4 + wv;
            if (u < 2 * RI2) {
                int ri = (u < RI2) ? u : (u - RI2);
                int r = ri >> 1, ii = ri & 1;
                const float* av = att_rel + r * B_BASES;
                const float* bs = basis + ii * C_DIM;
                float w1 = 0.f, w2 = 0.f;
                #pragma unroll
                for (int bb = 0; bb < B_BASES; ++bb) {
                    float a = av[bb];
                    w1 += a * bs[bb * 2 * C_DIM + lane];
                    w2 += a * bs[bb * 2 * C_DIM + 64 + lane];
                }
                const float* qk = (u < RI2) ? q_att : k_att;
                float s = w1 * qk[lane] + w2 * qk[64 + lane];
                #pragma unroll
                for (int off = 32; off; off >>= 1) s += __shfl_xor(s, off, 64);
                if (lane == 0) ws[((u < RI2) ? OFF_WQ : OFF_WK) + ri] = s;
            } else if (u < 2 * RI2 + 2) {
                int j = u - 2 * RI2;
                const float* er = lin_edge_W + j * C_DIM;
                float s = er[lane] * e_att[lane] + er[64 + lane] * e_att[64 + lane];
                #pragma unroll
                for (int off = 32; off; off >>= 1) s += __shfl_xor(s, off, 64);
                if (lane == 0) ws[OFF_LE + j] = s;
            }
        } else {
            int g = (b - (NB_HIST + 36)) * 256 + tid;   // 0..4095
            for (int idx = g; idx < 4 * C_DIM * HL_DIM; idx += 16 * 256) {
                int tt = idx / (C_DIM * HL_DIM);
                int rem = idx - tt * (C_DIM * HL_DIM);
                int cc = rem / HL_DIM, j = rem - cc * HL_DIM;
                ws[OFF_W0P + tt * (C_DIM * 40) + cc * 40 + j] = lin0_W[idx];
            }
            for (int idx = g; idx < 4 * HL_DIM * HL_DIM; idx += 16 * 256) {
                int tt = idx / (HL_DIM * HL_DIM);
                int rem = idx - tt * (HL_DIM * HL_DIM);
                int cc = rem / HL_DIM, j = rem - cc * HL_DIM;
                ws[OFF_W1P + tt * (HL_DIM * 40) + cc * 40 + j] = lin1_W[idx];
                ws[OFF_W2P + tt * (HL_DIM * 40) + cc * 40 + j] = lin2_W[idx];
            }
        }
        return;
    }

    __shared__ int lh[NB_HIST * 4];
    __shared__ int pre[4], tot[4], basel[4];
    __shared__ int wcnt[4][4];
    const int* hblk = (const int*)(ws + OFF_HBLK);
    for (int i = tid; i < NB_HIST * 4; i += 256) lh[i] = hblk[i];
    __syncthreads();
    if (tid < 4) {
        int run = 0, mypre = 0;
        for (int bb = 0; bb < NB_HIST; ++bb) {
            if (bb == b) mypre = run;
            run += lh[bb * 4 + tid];
        }
        pre[tid] = mypre;
        tot[tid] = run;
    }
    __syncthreads();
    if (tid == 0) {
        int t0 = tot[0], t1 = tot[1], t2 = tot[2];
        int b1 = ((t0 + 63) >> 6) << 6;
        int b2 = b1 + (((t1 + 63) >> 6) << 6);
        int b3 = b2 + (((t2 + 63) >> 6) << 6);
        basel[0] = 0; basel[1] = b1; basel[2] = b2; basel[3] = b3;
        if (b == 0) {
            int* meta = (int*)(ws + OFF_META);
            meta[0] = t0; meta[1] = t1; meta[2] = t2; meta[3] = tot[3];
            meta[4] = 0;  meta[5] = b1; meta[6] = b2; meta[7] = b3;
        }
    }
    __syncthreads();
    int n = b * 256 + tid;
    bool active = n < N_NODES;
    int ty = active ? node_type[n] : -1;
    int myrank = 0;
    #pragma unroll
    for (int t = 0; t < 4; ++t) {
        unsigned long long m = __ballot(ty == t);
        if (lane == 0) wcnt[wv][t] = __popcll(m);
        if (ty == t) myrank = __popcll(m & ((1ULL << lane) - 1ULL));
    }
    __syncthreads();
    if (active) {
        int prew = 0;
        for (int w2 = 0; w2 < wv; ++w2) prew += wcnt[w2][ty];
        int p = basel[ty] + pre[ty] + prew + myrank;
        ((int*)(ws + OFF_PERM))[n] = p;
        ((int*)(ws + OFF_INV))[p] = n;
    }
}

// D3 (k_escatter): r7 version — 512 threads x 391 blocks.
__global__ __launch_bounds__(512) void k_escatter(const float* __restrict__ x,
                                                  const int* __restrict__ edge_index,
                                                  const int* __restrict__ edge_type,
                                                  const float* __restrict__ edge_attr,
                                                  float* __restrict__ ws) {
    __shared__ int hist[NBUCK];
    __shared__ int sbase[NBUCK];
    __shared__ float swq[RI2], swk[RI2], sle[2];
    int tid = threadIdx.x;
    for (int i = tid; i < NBUCK; i += 512) hist[i] = 0;
    if (tid < RI2) { swq[tid] = ws[OFF_WQ + tid]; swk[tid] = ws[OFF_WK + tid]; }
    if (tid < 2) sle[tid] = ws[OFF_LE + tid];
    __syncthreads();

    const int* perm = (const int*)(ws + OFF_PERM);
    int base = blockIdx.x * EPB;
    int   rb[2], rm[2];
    float rex[2], rsx[2], rsy[2];
    #pragma unroll
    for (int k = 0; k < 2; ++k) {
        int e = base + k * 512 + tid;
        rb[k] = -1;
        if (e < N_EDGES) {
            int src = edge_index[e];
            int dst = edge_index[N_EDGES + e];
            int r   = edge_type[e];
            int p   = perm[dst];
            float2 ea = *(const float2*)(edge_attr + 2 * e);
            float2 xs = *(const float2*)(x + 2 * src);
            float2 xd = *(const float2*)(x + 2 * dst);
            float alpha = xd.x * swq[2 * r] + xd.y * swq[2 * r + 1]
                        + xs.x * swk[2 * r] + xs.y * swk[2 * r + 1]
                        + ea.x * sle[0]     + ea.y * sle[1];
            alpha = alpha > 0.f ? alpha : 0.2f * alpha;
            float ex = __expf(alpha);
            rb[k]  = p >> 6;
            rm[k]  = (r << 6) | (p & 63);
            rex[k] = ex;
            rsx[k] = ex * xs.x;
            rsy[k] = ex * xs.y;
            atomicAdd(&hist[rb[k]], 1);
        }
    }
    __syncthreads();
    int* gcur = (int*)(ws + OFF_ECUR);
    for (int i = tid; i < NBUCK; i += 512) {
        int c = hist[i];
        sbase[i] = (c > 0) ? atomicAdd(&gcur[i], c) : 0;
    }
    __syncthreads();
    float4* rec = (float4*)(ws + OFF_EREC);
    #pragma unroll
    for (int k = 0; k < 2; ++k) {
        if (rb[k] >= 0) {
            int slot = atomicAdd(&sbase[rb[k]], 1);
            rec[(size_t)rb[k] * CAP + slot] =
                make_float4(__int_as_float(rm[k]), rex[k], rsx[k], rsy[k]);
        }
    }
}

// D4 (k_node): r7 structure + basis trick — sT[70] projected to sB[24] via att_rel,
// then GEMM1' contracts K=24 against basis (raw input, L2-broadcast). 2.3x less
// GEMM1-path arithmetic; one extra barrier; LDS footprint unchanged.
__global__ __launch_bounds__(256, 4) void k_node(
        const float* __restrict__ ws, const float* __restrict__ basis,
        const float* __restrict__ att_rel, const float* __restrict__ conv_bias,
        const float* __restrict__ lin0_b, const float* __restrict__ lin1_b,
        const float* __restrict__ lin2_b, const float* __restrict__ fin_W,
        const float* __restrict__ fin_b, float* __restrict__ out) {
    __shared__ float L[LDS_FLOATS];
    int tid  = threadIdx.x;
    int lane = tid & 63;
    int wv   = tid >> 6;
    int p0   = blockIdx.x * 64;

    const int* meta = (const int*)(ws + OFF_META);
    int b1 = meta[5], b2 = meta[6], b3 = meta[7];
    int t  = (p0 >= b1) + (p0 >= b2) + (p0 >= b3);   // block-uniform
    int bp = meta[4 + t];
    int cnt = meta[t];

    // ---------- phase 0: zero sT+sB (contiguous 6392 floats) + den; stage FW/FB
    for (int i4 = tid; i4 < (RI2 * 68 + BI2 * 68) / 4; i4 += 256)
        *(float4*)&L[ST + i4 * 4] = make_float4(0.f, 0.f, 0.f, 0.f);
    if (tid < 64) L[SM_DINV + tid] = 0.f;
    if (tid >= 64 && tid < 142) {
        int i = tid - 64;
        if (i < 76) L[SM_FW + i] = fin_W[t * 76 + i];
        else        L[SM_FB + i - 76] = fin_b[t * 2 + i - 76];
    }
    __syncthreads();   // B1

    // ---------- phase 1: accumulate this bucket's edge records (LDS atomics)
    {
        int ecnt = ((const int*)(ws + OFF_ECUR))[blockIdx.x];
        const float4* rec = (const float4*)(ws + OFF_EREC) + (size_t)blockIdx.x * CAP;
        for (int i = tid; i < ecnt; i += 256) {
            float4 v = rec[i];
            int m = __float_as_int(v.x);
            int n = m & 63, r = m >> 6;
            atomicAdd(&L[ST + (2 * r) * 68 + n],     v.z);
            atomicAdd(&L[ST + (2 * r + 1) * 68 + n], v.w);
            atomicAdd(&L[SM_DINV + n],               v.y);
        }
    }
    __syncthreads();   // B2
    if (tid < 64) L[SM_DINV + tid] = 1.0f / (L[SM_DINV + tid] + 1e-16f);

    // ---------- phase 1.5: basis projection sB[2b+i][n] = sum_r att_rel[r,b]*sT[2r+i][n]
    // threads 0..127: (n = tid&63, i = tid>>6); att_rel loads are wave-uniform (s_load)
    if (tid < 128) {
        int n = tid & 63, ii = tid >> 6;
        float pb[B_BASES];
        #pragma unroll
        for (int bq = 0; bq < B_BASES; ++bq) pb[bq] = 0.f;
        #pragma unroll 5
        for (int r = 0; r < R_REL; ++r) {
            float s = L[ST + (2 * r + ii) * 68 + n];
            #pragma unroll
            for (int bq = 0; bq < B_BASES; ++bq)
                pb[bq] += s * att_rel[r * B_BASES + bq];
        }
        #pragma unroll
        for (int bq = 0; bq < B_BASES; ++bq)
            L[SB + (2 * bq + ii) * 68 + n] = pb[bq];
    }
    __syncthreads();   // B2b: sB complete

    // ---------- GEMM1': H[64n x 128c] = sB x basis — K=24, basis from L2 (broadcast)
    int ng = lane & 15, cg_ = lane >> 4;
    int c0 = wv * 32 + cg_ * 8;
    float acc[32];
    #pragma unroll
    for (int i = 0; i < 32; ++i) acc[i] = 0.f;
    #pragma unroll 4
    for (int kk = 0; kk < BI2; ++kk) {
        float4 a4 = *(const float4*)&L[SB + kk * 68 + ng * 4];
        float4 wa = *(const float4*)&basis[kk * 128 + c0];
        float4 wc = *(const float4*)&basis[kk * 128 + c0 + 4];
        float a_[4] = {a4.x, a4.y, a4.z, a4.w};
        float w_[8] = {wa.x, wa.y, wa.z, wa.w, wc.x, wc.y, wc.z, wc.w};
        #pragma unroll
        for (int ni = 0; ni < 4; ++ni)
            #pragma unroll
            for (int ci = 0; ci < 8; ++ci)
                acc[ni * 8 + ci] += a_[ni] * w_[ci];
    }
    __syncthreads();   // B3: sB/ST reads done; SM_DINV writes visible

    // epilogue 1: h = relu(acc*dinv + cb) -> H[c][n]
    {
        float4 dv = *(const float4*)&L[SM_DINV + ng * 4];
        float d_[4] = {dv.x, dv.y, dv.z, dv.w};
        #pragma unroll
        for (int ci = 0; ci < 8; ++ci) {
            float cb = conv_bias[c0 + ci];
            float4 hv;
            float h0 = acc[0 * 8 + ci] * d_[0] + cb;
            float h1 = acc[1 * 8 + ci] * d_[1] + cb;
            float h2 = acc[2 * 8 + ci] * d_[2] + cb;
            float h3 = acc[3 * 8 + ci] * d_[3] + cb;
            hv.x = h0 > 0.f ? h0 : 0.f;
            hv.y = h1 > 0.f ? h1 : 0.f;
            hv.z = h2 > 0.f ? h2 : 0.f;
            hv.w = h3 > 0.f ? h3 : 0.f;
            *(float4*)&L[HH + (c0 + ci) * 64 + ng * 4] = hv;
        }
    }
    __syncthreads();   // B4: H ready

    // ---------- GEMM2: y0[64n x 48j] = H x W0 — W0 from padded ws copy; waves 0..2
    int jg = lane >> 4;
    int j0 = wv * 16 + jg * 4;
    const float* W0g = ws + OFF_W0P + t * (C_DIM * 40);
    float acc2[16];
    #pragma unroll
    for (int i = 0; i < 16; ++i) acc2[i] = 0.f;
    if (wv < 3) {
        #pragma unroll 4
        for (int kk = 0; kk < C_DIM; ++kk) {
            float4 a4 = *(const float4*)&L[HH + kk * 64 + ng * 4];
            float4 w4 = *(const float4*)&W0g[kk * 40 + j0];
            float a_[4] = {a4.x, a4.y, a4.z, a4.w};
            float w_[4] = {w4.x, w4.y, w4.z, w4.w};
            #pragma unroll
            for (int ni = 0; ni < 4; ++ni)
                #pragma unroll
                for (int ji = 0; ji < 4; ++ji)
                    acc2[ni * 4 + ji] += a_[ni] * w_[ji];
        }
    }
    __syncthreads();   // B5: all H reads done

    // epilogue 2 (waves 0..2): relu(y0 + b0) -> Y0T over dead H rows
    if (wv < 3) {
        #pragma unroll
        for (int ji = 0; ji < 4; ++ji) {
            int j = j0 + ji;
            float bb = (j < HL_DIM) ? lin0_b[t * HL_DIM + j] : 0.f;
            float4 yv;
            float y0 = acc2[0 * 4 + ji] + bb;
            float y1 = acc2[1 * 4 + ji] + bb;
            float y2 = acc2[2 * 4 + ji] + bb;
            float y3 = acc2[3 * 4 + ji] + bb;
            yv.x = y0 > 0.f ? y0 : 0.f;
            yv.y = y1 > 0.f ? y1 : 0.f;
            yv.z = y2 > 0.f ? y2 : 0.f;
            yv.w = y3 > 0.f ? y3 : 0.f;
            *(float4*)&L[Y0T + j * 68 + ng * 4] = yv;
        }
    }
    __syncthreads();   // B6: Y0T complete

    // ---------- GEMM3: y1 = y0 x W1 (k=38); waves 0..2; write Y1T (disjoint)
    if (wv < 3) {
        const float* W1g = ws + OFF_W1P + t * (HL_DIM * 40);
        float acc3[16];
        #pragma unroll
        for (int i = 0; i < 16; ++i) acc3[i] = 0.f;
        #pragma unroll 2
        for (int kk = 0; kk < HL_DIM; ++kk) {
            float4 a4 = *(const float4*)&L[Y0T + kk * 68 + ng * 4];
            float4 w4 = *(const float4*)&W1g[kk * 40 + j0];
            float a_[4] = {a4.x, a4.y, a4.z, a4.w};
            float w_[4] = {w4.x, w4.y, w4.z, w4.w};
            #pragma unroll
            for (int ni = 0; ni < 4; ++ni)
                #pragma unroll
                for (int ji = 0; ji < 4; ++ji)
                    acc3[ni * 4 + ji] += a_[ni] * w_[ji];
        }
        #pragma unroll
        for (int ji = 0; ji < 4; ++ji) {
            int j = j0 + ji;
            float bb = (j < HL_DIM) ? lin1_b[t * HL_DIM + j] : 0.f;
            float4 yv;
            float y0 = acc3[0 * 4 + ji] + bb;
            float y1 = acc3[1 * 4 + ji] + bb;
            float y2 = acc3[2 * 4 + ji] + bb;
            float y3 = acc3[3 * 4 + ji] + bb;
            yv.x = y0 > 0.f ? y0 : 0.f;
            yv.y = y1 > 0.f ? y1 : 0.f;
            yv.z = y2 > 0.f ? y2 : 0.f;
            yv.w = y3 > 0.f ? y3 : 0.f;
            *(float4*)&L[Y1T + j * 68 + ng * 4] = yv;
        }
    }
    __syncthreads();   // B7: Y1T complete; Y0T reads done

    // ---------- GEMM4: y2 = y1 x W2 (no relu); waves 0..2; Y2T over dead Y0T
    if (wv < 3) {
        const float* W2g = ws + OFF_W2P + t * (HL_DIM * 40);
        float acc4[16];
        #pragma unroll
        for (int i = 0; i < 16; ++i) acc4[i] = 0.f;
        #pragma unroll 2
        for (int kk = 0; kk < HL_DIM; ++kk) {
            float4 a4 = *(const float4*)&L[Y1T + kk * 68 + ng * 4];
            float4 w4 = *(const float4*)&W2g[kk * 40 + j0];
            float a_[4] = {a4.x, a4.y, a4.z, a4.w};
            float w_[4] = {w4.x, w4.y, w4.z, w4.w};
            #pragma unroll
            for (int ni = 0; ni < 4; ++ni)
                #pragma unroll
                for (int ji = 0; ji < 4; ++ji)
                    acc4[ni * 4 + ji] += a_[ni] * w_[ji];
        }
        #pragma unroll
        for (int ji = 0; ji < 4; ++ji) {
            int j = j0 + ji;
            float bb = (j < HL_DIM) ? lin2_b[t * HL_DIM + j] : 0.f;
            float4 yv;
            yv.x = acc4[0 * 4 + ji] + bb;
            yv.y = acc4[1 * 4 + ji] + bb;
            yv.z = acc4[2 * 4 + ji] + bb;
            yv.w = acc4[3 * 4 + ji] + bb;
            *(float4*)&L[Y2T + j * 68 + ng * 4] = yv;
        }
    }
    __syncthreads();   // B8: Y2T complete

    // ---------- final: fin [38]->[2], thread-per-node (wave 0)
    if (tid < 64) {
        int p = p0 + tid;
        bool valid = (p - bp) < cnt;
        float o0 = L[SM_FB], o1 = L[SM_FB + 1];
        for (int jj = 0; jj < HL_DIM; ++jj) {
            float v = L[Y2T + jj * 68 + tid];
            float2 f = *(const float2*)&L[SM_FW + jj * 2];
            o0 += v * f.x;
            o1 += v * f.y;
        }
        if (t == 0) o1 = fabsf(o1);
        if (valid) {
            int orig = ((const int*)(ws + OFF_INV))[p];
            ((float2*)out)[orig] = make_float2(o0, o1);
        }
    }
}

extern "C" void kernel_launch(void* const* d_in, const int* in_sizes, int n_in,
                              void* d_out, int out_size, void* d_ws, size_t ws_size,
                              hipStream_t stream) {
    const float* x          = (const float*)d_in[0];
    const int*   edge_index = (const int*)  d_in[1];
    const int*   edge_type  = (const int*)  d_in[2];
    const float* edge_attr  = (const float*)d_in[3];
    const int*   node_type  = (const int*)  d_in[4];
    const float* basis      = (const float*)d_in[5];
    const float* att_rel    = (const float*)d_in[6];
    const float* q_att      = (const float*)d_in[7];
    const float* k_att      = (const float*)d_in[8];
    const float* e_att      = (const float*)d_in[9];
    const float* lin_edge_W = (const float*)d_in[10];
    const float* conv_bias  = (const float*)d_in[11];
    const float* lin0_W     = (const float*)d_in[12];
    const float* lin0_b     = (const float*)d_in[13];
    const float* lin1_W     = (const float*)d_in[14];
    const float* lin1_b     = (const float*)d_in[15];
    const float* lin2_W     = (const float*)d_in[16];
    const float* lin2_b     = (const float*)d_in[17];
    const float* fin_W      = (const float*)d_in[18];
    const float* fin_b      = (const float*)d_in[19];

    float* ws  = (float*)d_ws;
    float* out = (float*)d_out;

    k_hist    <<<NB_HIST + 1, 256, 0, stream>>>(node_type, ws);
    k_perm2   <<<NB_HIST + 36 + 16, 256, 0, stream>>>(node_type, basis, att_rel,
                                                      q_att, k_att, e_att, lin_edge_W,
                                                      lin0_W, lin1_W, lin2_W, ws);
    k_escatter<<<NEB, 512, 0, stream>>>(x, edge_index, edge_type, edge_attr, ws);
    k_node    <<<NBUCK, 256, 0, stream>>>(ws, basis, att_rel, conv_bias,
                                          lin0_b, lin1_b, lin2_b, fin_W, fin_b, out);
}